// Round 5
// baseline (449.709 us; speedup 1.0000x reference)
//
#include <hip/hip_runtime.h>

typedef unsigned short u16;
typedef __attribute__((ext_vector_type(4))) float f4;
typedef __attribute__((ext_vector_type(8))) short s8v;    // 8 x bf16 MFMA frag (4 VGPRs)
typedef __attribute__((ext_vector_type(4))) unsigned short u16x4;

#define DEVINL __device__ __forceinline__

DEVINL float b2f(u16 u) { union { unsigned i; float f; } x; x.i = ((unsigned)u) << 16; return x.f; }
DEVINL u16 f2b(float f) {
  union { float f; unsigned i; } x; x.f = f;
  unsigned r = 0x7FFFu + ((x.i >> 16) & 1u);
  return (u16)((x.i + r) >> 16);
}

#define GLD_LDS16(g, l)                                                        \
  __builtin_amdgcn_global_load_lds((__attribute__((address_space(1))) void*)(g), \
                                   (__attribute__((address_space(3))) void*)(l), 16, 0, 0)

// ---------------- transpose + fp32->bf16 cast: out[C,R] = cast(in[R,C]^T) ----------------
__global__ __launch_bounds__(256) void k_transpose(const float* __restrict__ in,
                                                   u16* __restrict__ out, int R, int C) {
  __shared__ float t[32][33];
  int tx = threadIdx.x & 31, ty = threadIdx.x >> 5;
  int c0 = blockIdx.x * 32, r0 = blockIdx.y * 32;
#pragma unroll
  for (int i = 0; i < 32; i += 8)
    t[ty + i][tx] = in[(long)(r0 + ty + i) * C + (c0 + tx)];
  __syncthreads();
#pragma unroll
  for (int i = 0; i < 32; i += 8)
    out[(long)(c0 + ty + i) * R + (r0 + tx)] = f2b(t[tx][ty + i]);
}

// ---------------- 3x 64x64 transposes in one launch (z selects) ----------------
__global__ __launch_bounds__(256) void k_transpose3(const float* __restrict__ i0,
                                                    const float* __restrict__ i1,
                                                    const float* __restrict__ i2,
                                                    u16* __restrict__ o0, u16* __restrict__ o1,
                                                    u16* __restrict__ o2) {
  const float* in = blockIdx.z == 0 ? i0 : (blockIdx.z == 1 ? i1 : i2);
  u16* out = blockIdx.z == 0 ? o0 : (blockIdx.z == 1 ? o1 : o2);
  __shared__ float t[32][33];
  int tx = threadIdx.x & 31, ty = threadIdx.x >> 5;
  int c0 = blockIdx.x * 32, r0 = blockIdx.y * 32;
#pragma unroll
  for (int i = 0; i < 32; i += 8)
    t[ty + i][tx] = in[(long)(r0 + ty + i) * 64 + (c0 + tx)];
  __syncthreads();
#pragma unroll
  for (int i = 0; i < 32; i += 8)
    out[(long)(c0 + ty + i) * 64 + (r0 + tx)] = f2b(t[tx][ty + i]);
}

// ---------------- bf16 V transpose: v [B,S,H,D] -> vt [B,H,D,S] ----------------
__global__ __launch_bounds__(256) void k_vtrans(const u16* __restrict__ v, u16* __restrict__ vt) {
  __shared__ u16 t[64][72];
  int bh = blockIdx.x, b = bh >> 4, h = bh & 15;
  int s0 = blockIdx.y * 64;
  int tid = threadIdx.x;
#pragma unroll
  for (int p = 0; p < 2; ++p) {
    int idx = p * 256 + tid;
    int sl = idx >> 3, c8 = (idx & 7) * 8;
    *(s8v*)(&t[sl][c8]) = *(const s8v*)(v + (((long)(b * 1024 + s0 + sl) * 16 + h) * 64) + c8);
  }
  __syncthreads();
#pragma unroll
  for (int p = 0; p < 2; ++p) {
    int idx = p * 256 + tid;
    int d = idx >> 3, c8 = (idx & 7) * 8;
    s8v o;
#pragma unroll
    for (int e = 0; e < 8; ++e) o[e] = (short)t[c8 + e][d];
    *(s8v*)(vt + ((long)bh * 64 + d) * 1024 + s0 + c8) = o;
  }
}

// ---------------- LayerNorm over E=1024, one row per block, bf16 out ----------------
__global__ __launch_bounds__(256) void k_layernorm(const float* __restrict__ x,
                                                   const float* __restrict__ g,
                                                   const float* __restrict__ be,
                                                   u16* __restrict__ out) {
  long row = blockIdx.x;
  int tid = threadIdx.x;
  f4 v = ((const f4*)(x + row * 1024))[tid];
  float s = v[0] + v[1] + v[2] + v[3];
  float s2 = v[0] * v[0] + v[1] * v[1] + v[2] * v[2] + v[3] * v[3];
#pragma unroll
  for (int off = 32; off > 0; off >>= 1) {
    s += __shfl_down(s, off, 64);
    s2 += __shfl_down(s2, off, 64);
  }
  __shared__ float red[8];
  int wv = tid >> 6, ln = tid & 63;
  if (ln == 0) { red[wv] = s; red[4 + wv] = s2; }
  __syncthreads();
  s = red[0] + red[1] + red[2] + red[3];
  s2 = red[4] + red[5] + red[6] + red[7];
  float mean = s * (1.0f / 1024.0f);
  float var = s2 * (1.0f / 1024.0f) - mean * mean;
  float rs = rsqrtf(var + 1e-5f);
  f4 gg = ((const f4*)g)[tid];
  f4 bb = ((const f4*)be)[tid];
  u16x4 o;
#pragma unroll
  for (int i = 0; i < 4; ++i) o[i] = f2b((v[i] - mean) * rs * gg[i] + bb[i]);
  ((u16x4*)(out + row * 1024))[tid] = o;
}

// ---------------- QKV: [131072,64] @ [64,64] x3, MFMA 16x16x32 bf16 ----------------
__global__ __launch_bounds__(256) void k_qkv(const u16* __restrict__ nx, const u16* __restrict__ WqT,
                                             const u16* __restrict__ WkT, const u16* __restrict__ WvT,
                                             u16* __restrict__ q, u16* __restrict__ k,
                                             u16* __restrict__ v) {
  int tid = threadIdx.x, lane = tid & 63, wave = tid >> 6;
  int quad = lane >> 4, l16 = lane & 15;
  long rbase = (long)blockIdx.x * 64 + wave * 16;
  s8v a0 = *(const s8v*)(nx + (rbase + l16) * 64 + quad * 8);
  s8v a1 = *(const s8v*)(nx + (rbase + l16) * 64 + 32 + quad * 8);
  const u16* Ws[3] = {WqT, WkT, WvT};
  u16* Os[3] = {q, k, v};
#pragma unroll
  for (int t = 0; t < 3; ++t) {
#pragma unroll
    for (int j = 0; j < 4; ++j) {
      s8v b0 = *(const s8v*)(Ws[t] + (j * 16 + l16) * 64 + quad * 8);
      s8v b1 = *(const s8v*)(Ws[t] + (j * 16 + l16) * 64 + 32 + quad * 8);
      f4 acc = {0.f, 0.f, 0.f, 0.f};
      acc = __builtin_amdgcn_mfma_f32_16x16x32_bf16(a0, b0, acc, 0, 0, 0);
      acc = __builtin_amdgcn_mfma_f32_16x16x32_bf16(a1, b1, acc, 0, 0, 0);
#pragma unroll
      for (int r = 0; r < 4; ++r)
        Os[t][(rbase + quad * 4 + r) * 64 + j * 16 + l16] = f2b(acc[r]);
    }
  }
}

// ---------------- MFMA flash attention (causal) ----------------
__global__ __launch_bounds__(256) void k_attn_mfma(const u16* __restrict__ q,
                                                   const u16* __restrict__ kk,
                                                   const u16* __restrict__ vt,
                                                   u16* __restrict__ o) {
  constexpr int LDK = 72;
  __shared__ u16 Ks[64 * LDK];
  __shared__ u16 Vt[64 * LDK];
  __shared__ u16 Ps[4][16 * LDK];
  int tid = threadIdx.x, lane = tid & 63, wave = tid >> 6;
  int quad = lane >> 4, l16 = lane & 15;
  int b = blockIdx.x >> 4, h = blockIdx.x & 15;
  int qi = (int)gridDim.y - 1 - (int)blockIdx.y;
  int q0 = qi * 64 + wave * 16;

  const u16* qp = q + (((long)(b * 1024 + q0 + l16)) * 16 + h) * 64;
  s8v aq0 = *(const s8v*)(qp + quad * 8);
  s8v aq1 = *(const s8v*)(qp + 32 + quad * 8);

  f4 O[4];
  float m_[4], l_[4];
#pragma unroll
  for (int jd = 0; jd < 4; ++jd) O[jd] = f4{0.f, 0.f, 0.f, 0.f};
#pragma unroll
  for (int r = 0; r < 4; ++r) { m_[r] = -__builtin_inff(); l_[r] = 0.f; }

  for (int kt = 0; kt <= qi; ++kt) {
    __syncthreads();
#pragma unroll
    for (int p = 0; p < 2; ++p) {
      int idx = p * 256 + tid;
      int row = idx >> 3, c8 = (idx & 7) * 8;
      *(s8v*)(Ks + row * LDK + c8) =
          *(const s8v*)(kk + (((long)(b * 1024 + kt * 64 + row)) * 16 + h) * 64 + c8);
      *(s8v*)(Vt + row * LDK + c8) =
          *(const s8v*)(vt + ((long)blockIdx.x * 64 + row) * 1024 + kt * 64 + c8);
    }
    __syncthreads();

    f4 sf[4];
    __builtin_amdgcn_s_setprio(1);
#pragma unroll
    for (int jn = 0; jn < 4; ++jn) {
      s8v b0 = *(const s8v*)(Ks + (jn * 16 + l16) * LDK + quad * 8);
      s8v b1 = *(const s8v*)(Ks + (jn * 16 + l16) * LDK + 32 + quad * 8);
      f4 acc = f4{0.f, 0.f, 0.f, 0.f};
      acc = __builtin_amdgcn_mfma_f32_16x16x32_bf16(aq0, b0, acc, 0, 0, 0);
      acc = __builtin_amdgcn_mfma_f32_16x16x32_bf16(aq1, b1, acc, 0, 0, 0);
      sf[jn] = acc;
    }
    __builtin_amdgcn_s_setprio(0);
    bool diag = (kt == qi);
    float rm[4];
#pragma unroll
    for (int r = 0; r < 4; ++r) rm[r] = -__builtin_inff();
#pragma unroll
    for (int jn = 0; jn < 4; ++jn)
#pragma unroll
      for (int r = 0; r < 4; ++r) {
        float v = sf[jn][r] * 0.03125f;
        if (diag && (jn * 16 + l16 > wave * 16 + quad * 4 + r)) v = -__builtin_inff();
        sf[jn][r] = v;
        rm[r] = fmaxf(rm[r], v);
      }
#pragma unroll
    for (int off = 1; off < 16; off <<= 1)
#pragma unroll
      for (int r = 0; r < 4; ++r) rm[r] = fmaxf(rm[r], __shfl_xor(rm[r], off, 64));
    float alpha[4], rs[4];
#pragma unroll
    for (int r = 0; r < 4; ++r) {
      float mn = fmaxf(m_[r], rm[r]);
      alpha[r] = __expf(m_[r] - mn);
      m_[r] = mn;
      rs[r] = 0.f;
    }
#pragma unroll
    for (int jn = 0; jn < 4; ++jn)
#pragma unroll
      for (int r = 0; r < 4; ++r) {
        float p = __expf(sf[jn][r] - m_[r]);
        rs[r] += p;
        Ps[wave][(quad * 4 + r) * LDK + jn * 16 + l16] = f2b(p);
      }
#pragma unroll
    for (int off = 1; off < 16; off <<= 1)
#pragma unroll
      for (int r = 0; r < 4; ++r) rs[r] += __shfl_xor(rs[r], off, 64);
#pragma unroll
    for (int r = 0; r < 4; ++r) l_[r] = l_[r] * alpha[r] + rs[r];
#pragma unroll
    for (int jd = 0; jd < 4; ++jd)
#pragma unroll
      for (int r = 0; r < 4; ++r) O[jd][r] *= alpha[r];
    asm volatile("s_waitcnt lgkmcnt(0)" ::: "memory");
    s8v p0 = *(const s8v*)(&Ps[wave][l16 * LDK + quad * 8]);
    s8v p1 = *(const s8v*)(&Ps[wave][l16 * LDK + 32 + quad * 8]);
    __builtin_amdgcn_s_setprio(1);
#pragma unroll
    for (int jd = 0; jd < 4; ++jd) {
      s8v b0 = *(const s8v*)(Vt + (jd * 16 + l16) * LDK + quad * 8);
      s8v b1 = *(const s8v*)(Vt + (jd * 16 + l16) * LDK + 32 + quad * 8);
      O[jd] = __builtin_amdgcn_mfma_f32_16x16x32_bf16(p0, b0, O[jd], 0, 0, 0);
      O[jd] = __builtin_amdgcn_mfma_f32_16x16x32_bf16(p1, b1, O[jd], 0, 0, 0);
    }
    __builtin_amdgcn_s_setprio(0);
  }
#pragma unroll
  for (int r = 0; r < 4; ++r) {
    float inv = 1.0f / l_[r];
    u16* op = o + (((long)(b * 1024 + q0 + quad * 4 + r)) * 16 + h) * 64;
#pragma unroll
    for (int jd = 0; jd < 4; ++jd) op[jd * 16 + l16] = f2b(O[jd][r] * inv);
  }
}

// ---------------- 256x256 8-phase GEMM, G4 swizzle (0 conflicts) + T1 XCD swizzle ----------
// Requires gridDim.x*gridDim.y % 8 == 0. XCD k gets a contiguous chunk of logical
// tiles (B panels L2-resident; A panels temporally-close reuse).
template <int EPI>
__global__ __launch_bounds__(512) void k_gemm256(const u16* __restrict__ A,
                                                 const u16* __restrict__ BT,
                                                 const float* __restrict__ bias,
                                                 const float* __restrict__ resid,
                                                 void* __restrict__ outp, int M, int N, int K,
                                                 int lda) {
  __shared__ __align__(16) u16 S[65536];  // 128 KiB
  int tid = threadIdx.x, lane = tid & 63, wave = tid >> 6;
  int l16 = lane & 15, quad = lane >> 4;
  int wm = wave >> 2, wn = wave & 3;
  // T1 bijective XCD swizzle (nwg % 8 == 0)
  int o_ = blockIdx.y * gridDim.x + blockIdx.x;
  int nwg_ = gridDim.x * gridDim.y, qq_ = nwg_ >> 3;
  int lid_ = (o_ & 7) * qq_ + (o_ >> 3);
  long bm = lid_ % gridDim.x, bn = lid_ / gridDim.x;
  int z = blockIdx.z;

  int rl = l16 & 7;
  int c0 = 8 * (quad ^ rl);
  int c1 = 8 * ((quad ^ 4) ^ rl);
  int rowA = (wm * 64 + l16) * 64;
  int rowB = (wn * 32 + l16) * 64;

  int Lb = tid * 16;
  int Ls = Lb ^ (((Lb >> 7) & 7) << 4);
  int r_ = Ls >> 7, kin = (Ls & 127) >> 1;
  const u16* pA = A + (bm * 256 + r_) * (long)lda + kin + (long)z * K;
  const u16* pB = BT + (bn * 256 + r_) * (long)lda + kin + (long)z * K;

  f4 acc[4][4][2];
#pragma unroll
  for (int q = 0; q < 4; ++q)
#pragma unroll
    for (int mi = 0; mi < 4; ++mi)
#pragma unroll
      for (int nj = 0; nj < 2; ++nj) acc[q][mi][nj] = f4{0.f, 0.f, 0.f, 0.f};
  s8v aF[4][2], bF[2][2][2];

#define BAR asm volatile("s_barrier" ::: "memory")
#define LGK0 asm volatile("s_waitcnt lgkmcnt(0)" ::: "memory")
#define WVM4 asm volatile("s_waitcnt vmcnt(4)" ::: "memory")
#define WVM0 asm volatile("s_waitcnt vmcnt(0)" ::: "memory")

#define STAGE(mat, half, t, buf)                                               \
  do {                                                                         \
    const u16* g_ = ((mat) ? pB : pA) + (long)(half) * 128 * lda + (t) * 64;   \
    char* l_ = ((char*)S) + ((buf) * 32768 + (mat) * 16384 + (half) * 8192) * 2 + wave * 1024; \
    GLD_LDS16(g_, l_);                                                         \
    GLD_LDS16(g_ + 64 * (long)lda, l_ + 8192);                                 \
  } while (0)

#define LDA(buf, mh)                                                           \
  do {                                                                         \
    const u16* p_ = S + (buf) * 32768 + (mh) * 8192 + rowA;                    \
    _Pragma("unroll") for (int mi = 0; mi < 4; ++mi) {                         \
      aF[mi][0] = *(const s8v*)(p_ + mi * 1024 + c0);                          \
      aF[mi][1] = *(const s8v*)(p_ + mi * 1024 + c1);                          \
    }                                                                          \
  } while (0)

#define LDB(buf, nh, set)                                                      \
  do {                                                                         \
    const u16* p_ = S + (buf) * 32768 + 16384 + (nh) * 8192 + rowB;            \
    _Pragma("unroll") for (int nj = 0; nj < 2; ++nj) {                         \
      bF[set][nj][0] = *(const s8v*)(p_ + nj * 1024 + c0);                     \
      bF[set][nj][1] = *(const s8v*)(p_ + nj * 1024 + c1);                     \
    }                                                                          \
  } while (0)

#define MM(q)                                                                  \
  do {                                                                         \
    _Pragma("unroll") for (int mi = 0; mi < 4; ++mi)                           \
        _Pragma("unroll") for (int nj = 0; nj < 2; ++nj) {                     \
      acc[q][mi][nj] = __builtin_amdgcn_mfma_f32_16x16x32_bf16(                \
          aF[mi][0], bF[(q) & 1][nj][0], acc[q][mi][nj], 0, 0, 0);             \
      acc[q][mi][nj] = __builtin_amdgcn_mfma_f32_16x16x32_bf16(                \
          aF[mi][1], bF[(q) & 1][nj][1], acc[q][mi][nj], 0, 0, 0);             \
    }                                                                          \
  } while (0)

#define PHASES(t, LAST)                                                        \
  LDA(0, 0); LDB(0, 0, 0); STAGE(0, 1, (t) + 1, 1);                            \
  BAR; LGK0; __builtin_amdgcn_s_setprio(1); MM(0); __builtin_amdgcn_s_setprio(0); BAR; \
  LDB(0, 1, 1); STAGE(1, 1, (t) + 1, 1);                                       \
  BAR; LGK0; __builtin_amdgcn_s_setprio(1); MM(1); __builtin_amdgcn_s_setprio(0); BAR; \
  LDA(0, 1); if (!(LAST)) STAGE(0, 0, (t) + 2, 0);                             \
  BAR; LGK0; __builtin_amdgcn_s_setprio(1); MM(2); __builtin_amdgcn_s_setprio(0); BAR; \
  if (!(LAST)) STAGE(1, 0, (t) + 2, 0);                                        \
  __builtin_amdgcn_s_setprio(1); MM(3); __builtin_amdgcn_s_setprio(0);         \
  if (LAST) { WVM0; } else { WVM4; }                                           \
  BAR;                                                                         \
  LDA(1, 0); LDB(1, 0, 0); if (!(LAST)) STAGE(0, 1, (t) + 2, 0);               \
  BAR; LGK0; __builtin_amdgcn_s_setprio(1); MM(0); __builtin_amdgcn_s_setprio(0); BAR; \
  LDB(1, 1, 1); if (!(LAST)) STAGE(1, 1, (t) + 2, 0);                          \
  BAR; LGK0; __builtin_amdgcn_s_setprio(1); MM(1); __builtin_amdgcn_s_setprio(0); BAR; \
  LDA(1, 1); if (!(LAST)) STAGE(0, 0, (t) + 3, 1);                             \
  BAR; LGK0; __builtin_amdgcn_s_setprio(1); MM(2); __builtin_amdgcn_s_setprio(0); BAR; \
  if (!(LAST)) STAGE(1, 0, (t) + 3, 1);                                        \
  __builtin_amdgcn_s_setprio(1); MM(3); __builtin_amdgcn_s_setprio(0);         \
  if (!(LAST)) { WVM4; BAR; }

  STAGE(0, 0, 0, 0);
  STAGE(1, 0, 0, 0);
  STAGE(0, 1, 0, 0);
  STAGE(1, 1, 0, 0);
  STAGE(0, 0, 1, 1);
  STAGE(1, 0, 1, 1);
  WVM4; BAR;

  int NI = K >> 7;
  for (int i = 0; i < NI - 1; ++i) {
    int t = 2 * i;
    PHASES(t, 0);
  }
  {
    int t = 2 * (NI - 1);
    PHASES(t, 1);
  }

#undef PHASES
#undef MM
#undef LDB
#undef LDA
#undef STAGE
#undef WVM0
#undef WVM4
#undef LGK0
#undef BAR

  float* P0 = (EPI == 0) ? ((float*)outp + (long)z * M * N) : nullptr;
#pragma unroll
  for (int q = 0; q < 4; ++q) {
    int mh = q >> 1, nh = q & 1;
#pragma unroll
    for (int mi = 0; mi < 4; ++mi) {
#pragma unroll
      for (int nj = 0; nj < 2; ++nj) {
        long row = bm * 256 + mh * 128 + wm * 64 + mi * 16 + quad * 4;
        int col = (int)bn * 256 + nh * 128 + wn * 32 + nj * 16 + l16;
        float bcol = 0.f;
        if (EPI != 0) bcol = bias[col];
#pragma unroll
        for (int rr = 0; rr < 4; ++rr) {
          float val = acc[q][mi][nj][rr] + bcol;
          if (EPI == 0) {
            P0[(row + rr) * (long)N + col] = val;
          } else if (EPI == 1) {
            ((u16*)outp)[(row + rr) * (long)N + col] = f2b(val > 0.f ? val : 0.f);
          } else {
            ((float*)outp)[(row + rr) * (long)N + col] =
                resid[(row + rr) * (long)N + col] + val;
          }
        }
      }
    }
  }
}

// ---------------- 256x128 4-phase GEMM + T1 XCD swizzle ----------------
__global__ __launch_bounds__(512) void k_gemm256n128(const u16* __restrict__ A,
                                                     const u16* __restrict__ BT,
                                                     const float* __restrict__ bias,
                                                     const float* __restrict__ resid,
                                                     float* __restrict__ outp,
                                                     int M, int N, int K, int lda) {
  __shared__ __align__(16) u16 S[49152];  // 96 KiB: [buf][A0|A1|B][128][64]
  int tid = threadIdx.x, lane = tid & 63, wave = tid >> 6;
  int l16 = lane & 15, quad = lane >> 4;
  int wm = wave >> 1, wn = wave & 1;
  // T1 bijective XCD swizzle (nwg % 8 == 0)
  int o_ = blockIdx.y * gridDim.x + blockIdx.x;
  int nwg_ = gridDim.x * gridDim.y, qq_ = nwg_ >> 3;
  int lid_ = (o_ & 7) * qq_ + (o_ >> 3);
  long bm = lid_ % gridDim.x, bn = lid_ / gridDim.x;

  int rl = l16 & 7;
  int c0 = 8 * (quad ^ rl);
  int c1 = 8 * ((quad ^ 4) ^ rl);
  int rowA = (wm >> 1) * 8192 + ((wm & 1) * 64 + l16) * 64;
  int rowB = 16384 + (wn * 64 + l16) * 64;

  int Lb = tid * 16;
  int Ls = Lb ^ (((Lb >> 7) & 7) << 4);
  int r_ = Ls >> 7, kin = (Ls & 127) >> 1;
  const u16* pA = A + (bm * 256 + r_) * (long)lda + kin;
  const u16* pB = BT + (bn * 128 + r_) * (long)lda + kin;

  f4 acc[4][4];
#pragma unroll
  for (int mi = 0; mi < 4; ++mi)
#pragma unroll
    for (int nj = 0; nj < 4; ++nj) acc[mi][nj] = f4{0.f, 0.f, 0.f, 0.f};
  s8v aF[4][2], bF[2][2];

#define BAR asm volatile("s_barrier" ::: "memory")
#define LGK0 asm volatile("s_waitcnt lgkmcnt(0)" ::: "memory")
#define WVM4 asm volatile("s_waitcnt vmcnt(4)" ::: "memory")
#define WVM0 asm volatile("s_waitcnt vmcnt(0)" ::: "memory")

#define STAGEA(t, buf)                                                         \
  do {                                                                         \
    const u16* g_ = pA + (t) * 64;                                             \
    char* l_ = ((char*)S) + (buf) * 49152 + wave * 1024;                       \
    GLD_LDS16(g_, l_);                                                         \
    GLD_LDS16(g_ + 64 * (long)lda, l_ + 8192);                                 \
    GLD_LDS16(g_ + 128 * (long)lda, l_ + 16384);                               \
    GLD_LDS16(g_ + 192 * (long)lda, l_ + 24576);                               \
  } while (0)

#define STAGEB(t, buf)                                                         \
  do {                                                                         \
    const u16* g_ = pB + (t) * 64;                                             \
    char* l_ = ((char*)S) + (buf) * 49152 + 32768 + wave * 1024;               \
    GLD_LDS16(g_, l_);                                                         \
    GLD_LDS16(g_ + 64 * (long)lda, l_ + 8192);                                 \
  } while (0)

#define LDAn(buf)                                                              \
  do {                                                                         \
    const u16* p_ = S + (buf) * 24576 + rowA;                                  \
    _Pragma("unroll") for (int mi = 0; mi < 4; ++mi) {                         \
      aF[mi][0] = *(const s8v*)(p_ + mi * 1024 + c0);                          \
      aF[mi][1] = *(const s8v*)(p_ + mi * 1024 + c1);                          \
    }                                                                          \
  } while (0)

#define LDBn(buf, nh)                                                          \
  do {                                                                         \
    const u16* p_ = S + (buf) * 24576 + rowB + (nh) * 2048;                    \
    _Pragma("unroll") for (int nj2 = 0; nj2 < 2; ++nj2) {                      \
      bF[nj2][0] = *(const s8v*)(p_ + nj2 * 1024 + c0);                        \
      bF[nj2][1] = *(const s8v*)(p_ + nj2 * 1024 + c1);                        \
    }                                                                          \
  } while (0)

#define MMn(nh)                                                                \
  do {                                                                         \
    _Pragma("unroll") for (int mi = 0; mi < 4; ++mi)                           \
        _Pragma("unroll") for (int nj2 = 0; nj2 < 2; ++nj2) {                  \
      acc[mi][(nh) * 2 + nj2] = __builtin_amdgcn_mfma_f32_16x16x32_bf16(       \
          aF[mi][0], bF[nj2][0], acc[mi][(nh) * 2 + nj2], 0, 0, 0);            \
      acc[mi][(nh) * 2 + nj2] = __builtin_amdgcn_mfma_f32_16x16x32_bf16(       \
          aF[mi][1], bF[nj2][1], acc[mi][(nh) * 2 + nj2], 0, 0, 0);            \
    }                                                                          \
  } while (0)

#define PHASES(t, LAST)                                                        \
  LDAn(0); LDBn(0, 0); STAGEB((t) + 1, 1);                                     \
  BAR; LGK0; __builtin_amdgcn_s_setprio(1); MMn(0); __builtin_amdgcn_s_setprio(0); BAR; \
  LDBn(0, 1); if (!(LAST)) STAGEA((t) + 2, 0);                                 \
  BAR; LGK0; __builtin_amdgcn_s_setprio(1); MMn(1); __builtin_amdgcn_s_setprio(0); \
  if (LAST) { WVM0; } else { WVM4; }                                           \
  BAR;                                                                         \
  LDAn(1); LDBn(1, 0); if (!(LAST)) STAGEB((t) + 2, 0);                        \
  BAR; LGK0; __builtin_amdgcn_s_setprio(1); MMn(0); __builtin_amdgcn_s_setprio(0); BAR; \
  LDBn(1, 1); if (!(LAST)) STAGEA((t) + 3, 1);                                 \
  BAR; LGK0; __builtin_amdgcn_s_setprio(1); MMn(1); __builtin_amdgcn_s_setprio(0); \
  if (!(LAST)) { WVM4; }                                                       \
  BAR;

  STAGEA(0, 0);
  STAGEB(0, 0);
  STAGEA(1, 1);
  WVM4; BAR;

  int NI = K >> 7;
  for (int i = 0; i < NI - 1; ++i) {
    int t = 2 * i;
    PHASES(t, 0);
  }
  {
    int t = 2 * (NI - 1);
    PHASES(t, 1);
  }

#undef PHASES
#undef MMn
#undef LDBn
#undef LDAn
#undef STAGEB
#undef STAGEA
#undef WVM0
#undef WVM4
#undef LGK0
#undef BAR

#pragma unroll
  for (int mi = 0; mi < 4; ++mi) {
#pragma unroll
    for (int nj = 0; nj < 4; ++nj) {
      long row = bm * 256 + wm * 64 + mi * 16 + quad * 4;
      int col = (int)bn * 128 + wn * 64 + nj * 16 + l16;
      float bcol = bias[col];
#pragma unroll
      for (int rr = 0; rr < 4; ++rr) {
        outp[(row + rr) * (long)N + col] =
            resid[(row + rr) * (long)N + col] + acc[mi][nj][rr] + bcol;
      }
    }
  }
}

extern "C" void kernel_launch(void* const* d_in, const int* in_sizes, int n_in, void* d_out,
                              int out_size, void* d_ws, size_t ws_size, hipStream_t stream) {
  const float* x = (const float*)d_in[0];
  const float* Wq = (const float*)d_in[1];
  const float* Wk = (const float*)d_in[2];
  const float* Wv = (const float*)d_in[3];
  const float* Wo = (const float*)d_in[4];
  const float* bo = (const float*)d_in[5];
  const float* W1 = (const float*)d_in[6];
  const float* b1 = (const float*)d_in[7];
  const float* W2 = (const float*)d_in[8];
  const float* b2 = (const float*)d_in[9];
  const float* g1 = (const float*)d_in[10];
  const float* be1 = (const float*)d_in[11];
  const float* g2 = (const float*)d_in[12];
  const float* be2 = (const float*)d_in[13];

  char* ws = (char*)d_ws;
  const size_t MB = 1ull << 20;
  u16* nx = (u16*)(ws + 0);            // 16 MB  LN1 out; reused as attn out
  u16* qb = (u16*)(ws + 16 * MB);      // 16 MB  q; reused as nx2
  u16* kb = (u16*)(ws + 32 * MB);      // 16 MB
  u16* vb = (u16*)(ws + 48 * MB);      // 16 MB
  float* x1 = (float*)(ws + 64 * MB);  // 32 MB  attn-sublayer output (fp32 residual)
  u16* h1 = (u16*)(ws + 96 * MB);      // 64 MB  MLP hidden (after attn)
  u16* vtr = (u16*)(ws + 96 * MB);     // 16 MB  V^T [B,H,D,S]; dead before h1 is written
  u16* WoT = (u16*)(ws + 160 * MB);    // 2 MB
  u16* W1T = (u16*)(ws + 162 * MB);    // 8 MB
  u16* W2T = (u16*)(ws + 170 * MB);    // 8 MB
  u16* WqT = (u16*)(ws + 178 * MB);
  u16* WkT = WqT + 64 * 64;
  u16* WvT = WkT + 64 * 64;
  u16* ob = nx;
  u16* nx2 = qb;

  k_transpose<<<dim3(32, 32), 256, 0, stream>>>(Wo, WoT, 1024, 1024);
  k_transpose<<<dim3(128, 32), 256, 0, stream>>>(W1, W1T, 1024, 4096);
  k_transpose<<<dim3(32, 128), 256, 0, stream>>>(W2, W2T, 4096, 1024);
  k_transpose3<<<dim3(2, 2, 3), 256, 0, stream>>>(Wq, Wk, Wv, WqT, WkT, WvT);

  k_layernorm<<<8192, 256, 0, stream>>>(x, g1, be1, nx);
  k_qkv<<<2048, 256, 0, stream>>>(nx, WqT, WkT, WvT, qb, kb, vb);
  k_vtrans<<<dim3(128, 16), 256, 0, stream>>>(vb, vtr);
  k_attn_mfma<<<dim3(128, 16), 256, 0, stream>>>(qb, kb, vtr, ob);
  k_gemm256n128<<<dim3(32, 8), 512, 0, stream>>>(ob, WoT, bo, x, x1, 8192, 1024, 1024, 1024);

  k_layernorm<<<8192, 256, 0, stream>>>(x1, g2, be2, nx2);
  k_gemm256<1><<<dim3(32, 16, 1), 512, 0, stream>>>(nx2, W1T, b1, nullptr, h1, 8192, 4096, 1024, 1024);
  k_gemm256n128<<<dim3(32, 8), 512, 0, stream>>>(h1, W2T, b2, x1, (float*)d_out, 8192, 1024, 4096, 4096);
}

// Round 6
// 393.033 us; speedup vs baseline: 1.1442x; 1.1442x over previous
//
#include <hip/hip_runtime.h>

typedef unsigned short u16;
typedef __attribute__((ext_vector_type(4))) float f4;
typedef __attribute__((ext_vector_type(8))) short s8v;    // 8 x bf16 MFMA frag (4 VGPRs)
typedef __attribute__((ext_vector_type(4))) unsigned short u16x4;

#define DEVINL __device__ __forceinline__

DEVINL float b2f(u16 u) { union { unsigned i; float f; } x; x.i = ((unsigned)u) << 16; return x.f; }
DEVINL u16 f2b(float f) {
  union { float f; unsigned i; } x; x.f = f;
  unsigned r = 0x7FFFu + ((x.i >> 16) & 1u);
  return (u16)((x.i + r) >> 16);
}

#define GLD_LDS16(g, l)                                                        \
  __builtin_amdgcn_global_load_lds((__attribute__((address_space(1))) void*)(g), \
                                   (__attribute__((address_space(3))) void*)(l), 16, 0, 0)

// ---------------- ALL weight transposes in ONE launch ----------------
// Linearized 32x32-tile transpose+cast for Wo(1024x1024), W1(1024x4096),
// W2(4096x1024), Wq/Wk/Wv(64x64). 1024+4096+4096+12 = 9228 blocks.
__global__ __launch_bounds__(256) void k_transpose_all(
    const float* __restrict__ Wo, const float* __restrict__ W1,
    const float* __restrict__ W2, const float* __restrict__ Wq,
    const float* __restrict__ Wk, const float* __restrict__ Wv,
    u16* __restrict__ WoT, u16* __restrict__ W1T, u16* __restrict__ W2T,
    u16* __restrict__ WqT, u16* __restrict__ WkT, u16* __restrict__ WvT) {
  int id = blockIdx.x;
  const float* in;
  u16* out;
  int R, C, bx, by;
  if (id < 1024) {
    in = Wo; out = WoT; R = 1024; C = 1024; bx = id & 31; by = id >> 5;
  } else if (id < 5120) {
    int t = id - 1024;
    in = W1; out = W1T; R = 1024; C = 4096; bx = t & 127; by = t >> 7;
  } else if (id < 9216) {
    int t = id - 5120;
    in = W2; out = W2T; R = 4096; C = 1024; bx = t & 31; by = t >> 5;
  } else {
    int t = id - 9216;
    int z = t >> 2;
    in = z == 0 ? Wq : (z == 1 ? Wk : Wv);
    out = z == 0 ? WqT : (z == 1 ? WkT : WvT);
    R = 64; C = 64; bx = t & 1; by = (t >> 1) & 1;
  }
  __shared__ float tt[32][33];
  int tx = threadIdx.x & 31, ty = threadIdx.x >> 5;
  int c0 = bx * 32, r0 = by * 32;
#pragma unroll
  for (int i = 0; i < 32; i += 8)
    tt[ty + i][tx] = in[(long)(r0 + ty + i) * C + (c0 + tx)];
  __syncthreads();
#pragma unroll
  for (int i = 0; i < 32; i += 8)
    out[(long)(c0 + ty + i) * R + (r0 + tx)] = f2b(tt[tx][ty + i]);
}

// ---------------- bf16 V transpose: v [B,S,H,D] -> vt [B,H,D,S] ----------------
__global__ __launch_bounds__(256) void k_vtrans(const u16* __restrict__ v, u16* __restrict__ vt) {
  __shared__ u16 t[64][72];
  int bh = blockIdx.x, b = bh >> 4, h = bh & 15;
  int s0 = blockIdx.y * 64;
  int tid = threadIdx.x;
#pragma unroll
  for (int p = 0; p < 2; ++p) {
    int idx = p * 256 + tid;
    int sl = idx >> 3, c8 = (idx & 7) * 8;
    *(s8v*)(&t[sl][c8]) = *(const s8v*)(v + (((long)(b * 1024 + s0 + sl) * 16 + h) * 64) + c8);
  }
  __syncthreads();
#pragma unroll
  for (int p = 0; p < 2; ++p) {
    int idx = p * 256 + tid;
    int d = idx >> 3, c8 = (idx & 7) * 8;
    s8v o;
#pragma unroll
    for (int e = 0; e < 8; ++e) o[e] = (short)t[c8 + e][d];
    *(s8v*)(vt + ((long)bh * 64 + d) * 1024 + s0 + c8) = o;
  }
}

// ---------------- LayerNorm over E=1024, one row per block, bf16 out ----------------
__global__ __launch_bounds__(256) void k_layernorm(const float* __restrict__ x,
                                                   const float* __restrict__ g,
                                                   const float* __restrict__ be,
                                                   u16* __restrict__ out) {
  long row = blockIdx.x;
  int tid = threadIdx.x;
  f4 v = ((const f4*)(x + row * 1024))[tid];
  float s = v[0] + v[1] + v[2] + v[3];
  float s2 = v[0] * v[0] + v[1] * v[1] + v[2] * v[2] + v[3] * v[3];
#pragma unroll
  for (int off = 32; off > 0; off >>= 1) {
    s += __shfl_down(s, off, 64);
    s2 += __shfl_down(s2, off, 64);
  }
  __shared__ float red[8];
  int wv = tid >> 6, ln = tid & 63;
  if (ln == 0) { red[wv] = s; red[4 + wv] = s2; }
  __syncthreads();
  s = red[0] + red[1] + red[2] + red[3];
  s2 = red[4] + red[5] + red[6] + red[7];
  float mean = s * (1.0f / 1024.0f);
  float var = s2 * (1.0f / 1024.0f) - mean * mean;
  float rs = rsqrtf(var + 1e-5f);
  f4 gg = ((const f4*)g)[tid];
  f4 bb = ((const f4*)be)[tid];
  u16x4 o;
#pragma unroll
  for (int i = 0; i < 4; ++i) o[i] = f2b((v[i] - mean) * rs * gg[i] + bb[i]);
  ((u16x4*)(out + row * 1024))[tid] = o;
}

// ---------------- QKV: [131072,64] @ [64,64] x3, MFMA 16x16x32 bf16 ----------------
__global__ __launch_bounds__(256) void k_qkv(const u16* __restrict__ nx, const u16* __restrict__ WqT,
                                             const u16* __restrict__ WkT, const u16* __restrict__ WvT,
                                             u16* __restrict__ q, u16* __restrict__ k,
                                             u16* __restrict__ v) {
  int tid = threadIdx.x, lane = tid & 63, wave = tid >> 6;
  int quad = lane >> 4, l16 = lane & 15;
  long rbase = (long)blockIdx.x * 64 + wave * 16;
  s8v a0 = *(const s8v*)(nx + (rbase + l16) * 64 + quad * 8);
  s8v a1 = *(const s8v*)(nx + (rbase + l16) * 64 + 32 + quad * 8);
  const u16* Ws[3] = {WqT, WkT, WvT};
  u16* Os[3] = {q, k, v};
#pragma unroll
  for (int t = 0; t < 3; ++t) {
#pragma unroll
    for (int j = 0; j < 4; ++j) {
      s8v b0 = *(const s8v*)(Ws[t] + (j * 16 + l16) * 64 + quad * 8);
      s8v b1 = *(const s8v*)(Ws[t] + (j * 16 + l16) * 64 + 32 + quad * 8);
      f4 acc = {0.f, 0.f, 0.f, 0.f};
      acc = __builtin_amdgcn_mfma_f32_16x16x32_bf16(a0, b0, acc, 0, 0, 0);
      acc = __builtin_amdgcn_mfma_f32_16x16x32_bf16(a1, b1, acc, 0, 0, 0);
#pragma unroll
      for (int r = 0; r < 4; ++r)
        Os[t][(rbase + quad * 4 + r) * 64 + j * 16 + l16] = f2b(acc[r]);
    }
  }
}

// ---------------- MFMA flash attention (causal) ----------------
__global__ __launch_bounds__(256) void k_attn_mfma(const u16* __restrict__ q,
                                                   const u16* __restrict__ kk,
                                                   const u16* __restrict__ vt,
                                                   u16* __restrict__ o) {
  constexpr int LDK = 72;
  __shared__ u16 Ks[64 * LDK];
  __shared__ u16 Vt[64 * LDK];
  __shared__ u16 Ps[4][16 * LDK];
  int tid = threadIdx.x, lane = tid & 63, wave = tid >> 6;
  int quad = lane >> 4, l16 = lane & 15;
  int b = blockIdx.x >> 4, h = blockIdx.x & 15;
  int qi = (int)gridDim.y - 1 - (int)blockIdx.y;
  int q0 = qi * 64 + wave * 16;

  const u16* qp = q + (((long)(b * 1024 + q0 + l16)) * 16 + h) * 64;
  s8v aq0 = *(const s8v*)(qp + quad * 8);
  s8v aq1 = *(const s8v*)(qp + 32 + quad * 8);

  f4 O[4];
  float m_[4], l_[4];
#pragma unroll
  for (int jd = 0; jd < 4; ++jd) O[jd] = f4{0.f, 0.f, 0.f, 0.f};
#pragma unroll
  for (int r = 0; r < 4; ++r) { m_[r] = -__builtin_inff(); l_[r] = 0.f; }

  for (int kt = 0; kt <= qi; ++kt) {
    __syncthreads();
#pragma unroll
    for (int p = 0; p < 2; ++p) {
      int idx = p * 256 + tid;
      int row = idx >> 3, c8 = (idx & 7) * 8;
      *(s8v*)(Ks + row * LDK + c8) =
          *(const s8v*)(kk + (((long)(b * 1024 + kt * 64 + row)) * 16 + h) * 64 + c8);
      *(s8v*)(Vt + row * LDK + c8) =
          *(const s8v*)(vt + ((long)blockIdx.x * 64 + row) * 1024 + kt * 64 + c8);
    }
    __syncthreads();

    f4 sf[4];
    __builtin_amdgcn_s_setprio(1);
#pragma unroll
    for (int jn = 0; jn < 4; ++jn) {
      s8v b0 = *(const s8v*)(Ks + (jn * 16 + l16) * LDK + quad * 8);
      s8v b1 = *(const s8v*)(Ks + (jn * 16 + l16) * LDK + 32 + quad * 8);
      f4 acc = f4{0.f, 0.f, 0.f, 0.f};
      acc = __builtin_amdgcn_mfma_f32_16x16x32_bf16(aq0, b0, acc, 0, 0, 0);
      acc = __builtin_amdgcn_mfma_f32_16x16x32_bf16(aq1, b1, acc, 0, 0, 0);
      sf[jn] = acc;
    }
    __builtin_amdgcn_s_setprio(0);
    bool diag = (kt == qi);
    float rm[4];
#pragma unroll
    for (int r = 0; r < 4; ++r) rm[r] = -__builtin_inff();
#pragma unroll
    for (int jn = 0; jn < 4; ++jn)
#pragma unroll
      for (int r = 0; r < 4; ++r) {
        float v = sf[jn][r] * 0.03125f;
        if (diag && (jn * 16 + l16 > wave * 16 + quad * 4 + r)) v = -__builtin_inff();
        sf[jn][r] = v;
        rm[r] = fmaxf(rm[r], v);
      }
#pragma unroll
    for (int off = 1; off < 16; off <<= 1)
#pragma unroll
      for (int r = 0; r < 4; ++r) rm[r] = fmaxf(rm[r], __shfl_xor(rm[r], off, 64));
    float alpha[4], rs[4];
#pragma unroll
    for (int r = 0; r < 4; ++r) {
      float mn = fmaxf(m_[r], rm[r]);
      alpha[r] = __expf(m_[r] - mn);
      m_[r] = mn;
      rs[r] = 0.f;
    }
#pragma unroll
    for (int jn = 0; jn < 4; ++jn)
#pragma unroll
      for (int r = 0; r < 4; ++r) {
        float p = __expf(sf[jn][r] - m_[r]);
        rs[r] += p;
        Ps[wave][(quad * 4 + r) * LDK + jn * 16 + l16] = f2b(p);
      }
#pragma unroll
    for (int off = 1; off < 16; off <<= 1)
#pragma unroll
      for (int r = 0; r < 4; ++r) rs[r] += __shfl_xor(rs[r], off, 64);
#pragma unroll
    for (int r = 0; r < 4; ++r) l_[r] = l_[r] * alpha[r] + rs[r];
#pragma unroll
    for (int jd = 0; jd < 4; ++jd)
#pragma unroll
      for (int r = 0; r < 4; ++r) O[jd][r] *= alpha[r];
    asm volatile("s_waitcnt lgkmcnt(0)" ::: "memory");
    s8v p0 = *(const s8v*)(&Ps[wave][l16 * LDK + quad * 8]);
    s8v p1 = *(const s8v*)(&Ps[wave][l16 * LDK + 32 + quad * 8]);
    __builtin_amdgcn_s_setprio(1);
#pragma unroll
    for (int jd = 0; jd < 4; ++jd) {
      s8v b0 = *(const s8v*)(Vt + (jd * 16 + l16) * LDK + quad * 8);
      s8v b1 = *(const s8v*)(Vt + (jd * 16 + l16) * LDK + 32 + quad * 8);
      O[jd] = __builtin_amdgcn_mfma_f32_16x16x32_bf16(p0, b0, O[jd], 0, 0, 0);
      O[jd] = __builtin_amdgcn_mfma_f32_16x16x32_bf16(p1, b1, O[jd], 0, 0, 0);
    }
    __builtin_amdgcn_s_setprio(0);
  }
#pragma unroll
  for (int r = 0; r < 4; ++r) {
    float inv = 1.0f / l_[r];
    u16* op = o + (((long)(b * 1024 + q0 + quad * 4 + r)) * 16 + h) * 64;
#pragma unroll
    for (int jd = 0; jd < 4; ++jd) op[jd * 16 + l16] = f2b(O[jd][r] * inv);
  }
}

// ---------------- 256x256 8-phase GEMM, G4 swizzle (0 conflicts), default block map ----
// (T1 XCD swizzle REVERTED: r5 measured FETCH 82->283 MB, dur +14 us. Default
//  o_%8==bm%8 mapping already gives each XCD a small strided A slice + L3 B reuse.)
template <int EPI>
__global__ __launch_bounds__(512) void k_gemm256(const u16* __restrict__ A,
                                                 const u16* __restrict__ BT,
                                                 const float* __restrict__ bias,
                                                 const float* __restrict__ resid,
                                                 void* __restrict__ outp, int M, int N, int K,
                                                 int lda) {
  __shared__ __align__(16) u16 S[65536];  // 128 KiB
  int tid = threadIdx.x, lane = tid & 63, wave = tid >> 6;
  int l16 = lane & 15, quad = lane >> 4;
  int wm = wave >> 2, wn = wave & 3;
  long bm = blockIdx.x, bn = blockIdx.y;
  int z = blockIdx.z;

  int rl = l16 & 7;
  int c0 = 8 * (quad ^ rl);
  int c1 = 8 * ((quad ^ 4) ^ rl);
  int rowA = (wm * 64 + l16) * 64;
  int rowB = (wn * 32 + l16) * 64;

  int Lb = tid * 16;
  int Ls = Lb ^ (((Lb >> 7) & 7) << 4);
  int r_ = Ls >> 7, kin = (Ls & 127) >> 1;
  const u16* pA = A + (bm * 256 + r_) * (long)lda + kin + (long)z * K;
  const u16* pB = BT + (bn * 256 + r_) * (long)lda + kin + (long)z * K;

  f4 acc[4][4][2];
#pragma unroll
  for (int q = 0; q < 4; ++q)
#pragma unroll
    for (int mi = 0; mi < 4; ++mi)
#pragma unroll
      for (int nj = 0; nj < 2; ++nj) acc[q][mi][nj] = f4{0.f, 0.f, 0.f, 0.f};
  s8v aF[4][2], bF[2][2][2];

#define BAR asm volatile("s_barrier" ::: "memory")
#define LGK0 asm volatile("s_waitcnt lgkmcnt(0)" ::: "memory")
#define WVM4 asm volatile("s_waitcnt vmcnt(4)" ::: "memory")
#define WVM0 asm volatile("s_waitcnt vmcnt(0)" ::: "memory")

#define STAGE(mat, half, t, buf)                                               \
  do {                                                                         \
    const u16* g_ = ((mat) ? pB : pA) + (long)(half) * 128 * lda + (t) * 64;   \
    char* l_ = ((char*)S) + ((buf) * 32768 + (mat) * 16384 + (half) * 8192) * 2 + wave * 1024; \
    GLD_LDS16(g_, l_);                                                         \
    GLD_LDS16(g_ + 64 * (long)lda, l_ + 8192);                                 \
  } while (0)

#define LDA(buf, mh)                                                           \
  do {                                                                         \
    const u16* p_ = S + (buf) * 32768 + (mh) * 8192 + rowA;                    \
    _Pragma("unroll") for (int mi = 0; mi < 4; ++mi) {                         \
      aF[mi][0] = *(const s8v*)(p_ + mi * 1024 + c0);                          \
      aF[mi][1] = *(const s8v*)(p_ + mi * 1024 + c1);                          \
    }                                                                          \
  } while (0)

#define LDB(buf, nh, set)                                                      \
  do {                                                                         \
    const u16* p_ = S + (buf) * 32768 + 16384 + (nh) * 8192 + rowB;            \
    _Pragma("unroll") for (int nj = 0; nj < 2; ++nj) {                         \
      bF[set][nj][0] = *(const s8v*)(p_ + nj * 1024 + c0);                     \
      bF[set][nj][1] = *(const s8v*)(p_ + nj * 1024 + c1);                     \
    }                                                                          \
  } while (0)

#define MM(q)                                                                  \
  do {                                                                         \
    _Pragma("unroll") for (int mi = 0; mi < 4; ++mi)                           \
        _Pragma("unroll") for (int nj = 0; nj < 2; ++nj) {                     \
      acc[q][mi][nj] = __builtin_amdgcn_mfma_f32_16x16x32_bf16(                \
          aF[mi][0], bF[(q) & 1][nj][0], acc[q][mi][nj], 0, 0, 0);             \
      acc[q][mi][nj] = __builtin_amdgcn_mfma_f32_16x16x32_bf16(                \
          aF[mi][1], bF[(q) & 1][nj][1], acc[q][mi][nj], 0, 0, 0);             \
    }                                                                          \
  } while (0)

#define PHASES(t, LAST)                                                        \
  LDA(0, 0); LDB(0, 0, 0); STAGE(0, 1, (t) + 1, 1);                            \
  BAR; LGK0; __builtin_amdgcn_s_setprio(1); MM(0); __builtin_amdgcn_s_setprio(0); BAR; \
  LDB(0, 1, 1); STAGE(1, 1, (t) + 1, 1);                                       \
  BAR; LGK0; __builtin_amdgcn_s_setprio(1); MM(1); __builtin_amdgcn_s_setprio(0); BAR; \
  LDA(0, 1); if (!(LAST)) STAGE(0, 0, (t) + 2, 0);                             \
  BAR; LGK0; __builtin_amdgcn_s_setprio(1); MM(2); __builtin_amdgcn_s_setprio(0); BAR; \
  if (!(LAST)) STAGE(1, 0, (t) + 2, 0);                                        \
  __builtin_amdgcn_s_setprio(1); MM(3); __builtin_amdgcn_s_setprio(0);         \
  if (LAST) { WVM0; } else { WVM4; }                                           \
  BAR;                                                                         \
  LDA(1, 0); LDB(1, 0, 0); if (!(LAST)) STAGE(0, 1, (t) + 2, 0);               \
  BAR; LGK0; __builtin_amdgcn_s_setprio(1); MM(0); __builtin_amdgcn_s_setprio(0); BAR; \
  LDB(1, 1, 1); if (!(LAST)) STAGE(1, 1, (t) + 2, 0);                          \
  BAR; LGK0; __builtin_amdgcn_s_setprio(1); MM(1); __builtin_amdgcn_s_setprio(0); BAR; \
  LDA(1, 1); if (!(LAST)) STAGE(0, 0, (t) + 3, 1);                             \
  BAR; LGK0; __builtin_amdgcn_s_setprio(1); MM(2); __builtin_amdgcn_s_setprio(0); BAR; \
  if (!(LAST)) STAGE(1, 0, (t) + 3, 1);                                        \
  __builtin_amdgcn_s_setprio(1); MM(3); __builtin_amdgcn_s_setprio(0);         \
  if (!(LAST)) { WVM4; BAR; }

  STAGE(0, 0, 0, 0);
  STAGE(1, 0, 0, 0);
  STAGE(0, 1, 0, 0);
  STAGE(1, 1, 0, 0);
  STAGE(0, 0, 1, 1);
  STAGE(1, 0, 1, 1);
  WVM4; BAR;

  int NI = K >> 7;
  for (int i = 0; i < NI - 1; ++i) {
    int t = 2 * i;
    PHASES(t, 0);
  }
  {
    int t = 2 * (NI - 1);
    PHASES(t, 1);
  }

#undef PHASES
#undef MM
#undef LDB
#undef LDA
#undef STAGE
#undef WVM0
#undef WVM4
#undef LGK0
#undef BAR

  float* P0 = (EPI == 0) ? ((float*)outp + (long)z * M * N) : nullptr;
#pragma unroll
  for (int q = 0; q < 4; ++q) {
    int mh = q >> 1, nh = q & 1;
#pragma unroll
    for (int mi = 0; mi < 4; ++mi) {
#pragma unroll
      for (int nj = 0; nj < 2; ++nj) {
        long row = bm * 256 + mh * 128 + wm * 64 + mi * 16 + quad * 4;
        int col = (int)bn * 256 + nh * 128 + wn * 32 + nj * 16 + l16;
        float bcol = 0.f;
        if (EPI != 0) bcol = bias[col];
#pragma unroll
        for (int rr = 0; rr < 4; ++rr) {
          float val = acc[q][mi][nj][rr] + bcol;
          if (EPI == 0) {
            P0[(row + rr) * (long)N + col] = val;
          } else if (EPI == 1) {
            ((u16*)outp)[(row + rr) * (long)N + col] = f2b(val > 0.f ? val : 0.f);
          } else {
            ((float*)outp)[(row + rr) * (long)N + col] =
                resid[(row + rr) * (long)N + col] + val;
          }
        }
      }
    }
  }
}

// ---------------- 256x128 4-phase GEMM, default block map (T1 reverted) ----------------
__global__ __launch_bounds__(512) void k_gemm256n128(const u16* __restrict__ A,
                                                     const u16* __restrict__ BT,
                                                     const float* __restrict__ bias,
                                                     const float* __restrict__ resid,
                                                     float* __restrict__ outp,
                                                     int M, int N, int K, int lda) {
  __shared__ __align__(16) u16 S[49152];  // 96 KiB: [buf][A0|A1|B][128][64]
  int tid = threadIdx.x, lane = tid & 63, wave = tid >> 6;
  int l16 = lane & 15, quad = lane >> 4;
  int wm = wave >> 1, wn = wave & 1;
  long bm = blockIdx.x, bn = blockIdx.y;

  int rl = l16 & 7;
  int c0 = 8 * (quad ^ rl);
  int c1 = 8 * ((quad ^ 4) ^ rl);
  int rowA = (wm >> 1) * 8192 + ((wm & 1) * 64 + l16) * 64;
  int rowB = 16384 + (wn * 64 + l16) * 64;

  int Lb = tid * 16;
  int Ls = Lb ^ (((Lb >> 7) & 7) << 4);
  int r_ = Ls >> 7, kin = (Ls & 127) >> 1;
  const u16* pA = A + (bm * 256 + r_) * (long)lda + kin;
  const u16* pB = BT + (bn * 128 + r_) * (long)lda + kin;

  f4 acc[4][4];
#pragma unroll
  for (int mi = 0; mi < 4; ++mi)
#pragma unroll
    for (int nj = 0; nj < 4; ++nj) acc[mi][nj] = f4{0.f, 0.f, 0.f, 0.f};
  s8v aF[4][2], bF[2][2];

#define BAR asm volatile("s_barrier" ::: "memory")
#define LGK0 asm volatile("s_waitcnt lgkmcnt(0)" ::: "memory")
#define WVM4 asm volatile("s_waitcnt vmcnt(4)" ::: "memory")
#define WVM0 asm volatile("s_waitcnt vmcnt(0)" ::: "memory")

#define STAGEA(t, buf)                                                         \
  do {                                                                         \
    const u16* g_ = pA + (t) * 64;                                             \
    char* l_ = ((char*)S) + (buf) * 49152 + wave * 1024;                       \
    GLD_LDS16(g_, l_);                                                         \
    GLD_LDS16(g_ + 64 * (long)lda, l_ + 8192);                                 \
    GLD_LDS16(g_ + 128 * (long)lda, l_ + 16384);                               \
    GLD_LDS16(g_ + 192 * (long)lda, l_ + 24576);                               \
  } while (0)

#define STAGEB(t, buf)                                                         \
  do {                                                                         \
    const u16* g_ = pB + (t) * 64;                                             \
    char* l_ = ((char*)S) + (buf) * 49152 + 32768 + wave * 1024;               \
    GLD_LDS16(g_, l_);                                                         \
    GLD_LDS16(g_ + 64 * (long)lda, l_ + 8192);                                 \
  } while (0)

#define LDAn(buf)                                                              \
  do {                                                                         \
    const u16* p_ = S + (buf) * 24576 + rowA;                                  \
    _Pragma("unroll") for (int mi = 0; mi < 4; ++mi) {                         \
      aF[mi][0] = *(const s8v*)(p_ + mi * 1024 + c0);                          \
      aF[mi][1] = *(const s8v*)(p_ + mi * 1024 + c1);                          \
    }                                                                          \
  } while (0)

#define LDBn(buf, nh)                                                          \
  do {                                                                         \
    const u16* p_ = S + (buf) * 24576 + rowB + (nh) * 2048;                    \
    _Pragma("unroll") for (int nj2 = 0; nj2 < 2; ++nj2) {                      \
      bF[nj2][0] = *(const s8v*)(p_ + nj2 * 1024 + c0);                        \
      bF[nj2][1] = *(const s8v*)(p_ + nj2 * 1024 + c1);                        \
    }                                                                          \
  } while (0)

#define MMn(nh)                                                                \
  do {                                                                         \
    _Pragma("unroll") for (int mi = 0; mi < 4; ++mi)                           \
        _Pragma("unroll") for (int nj2 = 0; nj2 < 2; ++nj2) {                  \
      acc[mi][(nh) * 2 + nj2] = __builtin_amdgcn_mfma_f32_16x16x32_bf16(       \
          aF[mi][0], bF[nj2][0], acc[mi][(nh) * 2 + nj2], 0, 0, 0);            \
      acc[mi][(nh) * 2 + nj2] = __builtin_amdgcn_mfma_f32_16x16x32_bf16(       \
          aF[mi][1], bF[nj2][1], acc[mi][(nh) * 2 + nj2], 0, 0, 0);            \
    }                                                                          \
  } while (0)

#define PHASES(t, LAST)                                                        \
  LDAn(0); LDBn(0, 0); STAGEB((t) + 1, 1);                                     \
  BAR; LGK0; __builtin_amdgcn_s_setprio(1); MMn(0); __builtin_amdgcn_s_setprio(0); BAR; \
  LDBn(0, 1); if (!(LAST)) STAGEA((t) + 2, 0);                                 \
  BAR; LGK0; __builtin_amdgcn_s_setprio(1); MMn(1); __builtin_amdgcn_s_setprio(0); \
  if (LAST) { WVM0; } else { WVM4; }                                           \
  BAR;                                                                         \
  LDAn(1); LDBn(1, 0); if (!(LAST)) STAGEB((t) + 2, 0);                        \
  BAR; LGK0; __builtin_amdgcn_s_setprio(1); MMn(0); __builtin_amdgcn_s_setprio(0); BAR; \
  LDBn(1, 1); if (!(LAST)) STAGEA((t) + 3, 1);                                 \
  BAR; LGK0; __builtin_amdgcn_s_setprio(1); MMn(1); __builtin_amdgcn_s_setprio(0); \
  if (!(LAST)) { WVM4; }                                                       \
  BAR;

  STAGEA(0, 0);
  STAGEB(0, 0);
  STAGEA(1, 1);
  WVM4; BAR;

  int NI = K >> 7;
  for (int i = 0; i < NI - 1; ++i) {
    int t = 2 * i;
    PHASES(t, 0);
  }
  {
    int t = 2 * (NI - 1);
    PHASES(t, 1);
  }

#undef PHASES
#undef MMn
#undef LDBn
#undef LDAn
#undef STAGEB
#undef STAGEA
#undef WVM0
#undef WVM4
#undef LGK0
#undef BAR

#pragma unroll
  for (int mi = 0; mi < 4; ++mi) {
#pragma unroll
    for (int nj = 0; nj < 4; ++nj) {
      long row = bm * 256 + wm * 64 + mi * 16 + quad * 4;
      int col = (int)bn * 128 + wn * 64 + nj * 16 + l16;
      float bcol = bias[col];
#pragma unroll
      for (int rr = 0; rr < 4; ++rr) {
        outp[(row + rr) * (long)N + col] =
            resid[(row + rr) * (long)N + col] + acc[mi][nj][rr] + bcol;
      }
    }
  }
}

extern "C" void kernel_launch(void* const* d_in, const int* in_sizes, int n_in, void* d_out,
                              int out_size, void* d_ws, size_t ws_size, hipStream_t stream) {
  const float* x = (const float*)d_in[0];
  const float* Wq = (const float*)d_in[1];
  const float* Wk = (const float*)d_in[2];
  const float* Wv = (const float*)d_in[3];
  const float* Wo = (const float*)d_in[4];
  const float* bo = (const float*)d_in[5];
  const float* W1 = (const float*)d_in[6];
  const float* b1 = (const float*)d_in[7];
  const float* W2 = (const float*)d_in[8];
  const float* b2 = (const float*)d_in[9];
  const float* g1 = (const float*)d_in[10];
  const float* be1 = (const float*)d_in[11];
  const float* g2 = (const float*)d_in[12];
  const float* be2 = (const float*)d_in[13];

  char* ws = (char*)d_ws;
  const size_t MB = 1ull << 20;
  u16* nx = (u16*)(ws + 0);            // 16 MB  LN1 out; reused as attn out
  u16* qb = (u16*)(ws + 16 * MB);      // 16 MB  q; reused as nx2
  u16* kb = (u16*)(ws + 32 * MB);      // 16 MB
  u16* vb = (u16*)(ws + 48 * MB);      // 16 MB
  float* x1 = (float*)(ws + 64 * MB);  // 32 MB  attn-sublayer output (fp32 residual)
  u16* h1 = (u16*)(ws + 96 * MB);      // 64 MB  MLP hidden (after attn)
  u16* vtr = (u16*)(ws + 96 * MB);     // 16 MB  V^T [B,H,D,S]; dead before h1 is written
  u16* WoT = (u16*)(ws + 160 * MB);    // 2 MB
  u16* W1T = (u16*)(ws + 162 * MB);    // 8 MB
  u16* W2T = (u16*)(ws + 170 * MB);    // 8 MB
  u16* WqT = (u16*)(ws + 178 * MB);
  u16* WkT = WqT + 64 * 64;
  u16* WvT = WkT + 64 * 64;
  u16* ob = nx;
  u16* nx2 = qb;

  k_transpose_all<<<9228, 256, 0, stream>>>(Wo, W1, W2, Wq, Wk, Wv, WoT, W1T, W2T, WqT, WkT, WvT);

  k_layernorm<<<8192, 256, 0, stream>>>(x, g1, be1, nx);
  k_qkv<<<2048, 256, 0, stream>>>(nx, WqT, WkT, WvT, qb, kb, vb);
  k_vtrans<<<dim3(128, 16), 256, 0, stream>>>(vb, vtr);
  k_attn_mfma<<<dim3(128, 16), 256, 0, stream>>>(qb, kb, vtr, ob);
  k_gemm256n128<<<dim3(32, 8), 512, 0, stream>>>(ob, WoT, bo, x, x1, 8192, 1024, 1024, 1024);

  k_layernorm<<<8192, 256, 0, stream>>>(x1, g2, be2, nx2);
  k_gemm256<1><<<dim3(32, 16, 1), 512, 0, stream>>>(nx2, W1T, b1, nullptr, h1, 8192, 4096, 1024, 1024);
  k_gemm256n128<<<dim3(32, 8), 512, 0, stream>>>(h1, W2T, b2, x1, (float*)d_out, 8192, 1024, 4096, 4096);
}

// Round 7
// 386.538 us; speedup vs baseline: 1.1634x; 1.0168x over previous
//
#include <hip/hip_runtime.h>

typedef unsigned short u16;
typedef __attribute__((ext_vector_type(4))) float f4;
typedef __attribute__((ext_vector_type(8))) short s8v;    // 8 x bf16 MFMA frag (4 VGPRs)
typedef __attribute__((ext_vector_type(4))) unsigned short u16x4;

#define DEVINL __device__ __forceinline__

DEVINL float b2f(u16 u) { union { unsigned i; float f; } x; x.i = ((unsigned)u) << 16; return x.f; }
DEVINL u16 f2b(float f) {
  union { float f; unsigned i; } x; x.f = f;
  unsigned r = 0x7FFFu + ((x.i >> 16) & 1u);
  return (u16)((x.i + r) >> 16);
}

#define GLD_LDS16(g, l)                                                        \
  __builtin_amdgcn_global_load_lds((__attribute__((address_space(1))) void*)(g), \
                                   (__attribute__((address_space(3))) void*)(l), 16, 0, 0)

// ---------------- ALL weight transposes in ONE launch ----------------
__global__ __launch_bounds__(256) void k_transpose_all(
    const float* __restrict__ Wo, const float* __restrict__ W1,
    const float* __restrict__ W2, const float* __restrict__ Wq,
    const float* __restrict__ Wk, const float* __restrict__ Wv,
    u16* __restrict__ WoT, u16* __restrict__ W1T, u16* __restrict__ W2T,
    u16* __restrict__ WqT, u16* __restrict__ WkT, u16* __restrict__ WvT) {
  int id = blockIdx.x;
  const float* in;
  u16* out;
  int R, C, bx, by;
  if (id < 1024) {
    in = Wo; out = WoT; R = 1024; C = 1024; bx = id & 31; by = id >> 5;
  } else if (id < 5120) {
    int t = id - 1024;
    in = W1; out = W1T; R = 1024; C = 4096; bx = t & 127; by = t >> 7;
  } else if (id < 9216) {
    int t = id - 5120;
    in = W2; out = W2T; R = 4096; C = 1024; bx = t & 31; by = t >> 5;
  } else {
    int t = id - 9216;
    int z = t >> 2;
    in = z == 0 ? Wq : (z == 1 ? Wk : Wv);
    out = z == 0 ? WqT : (z == 1 ? WkT : WvT);
    R = 64; C = 64; bx = t & 1; by = (t >> 1) & 1;
  }
  __shared__ float tt[32][33];
  int tx = threadIdx.x & 31, ty = threadIdx.x >> 5;
  int c0 = bx * 32, r0 = by * 32;
#pragma unroll
  for (int i = 0; i < 32; i += 8)
    tt[ty + i][tx] = in[(long)(r0 + ty + i) * C + (c0 + tx)];
  __syncthreads();
#pragma unroll
  for (int i = 0; i < 32; i += 8)
    out[(long)(c0 + ty + i) * R + (r0 + tx)] = f2b(tt[tx][ty + i]);
}

// ---------------- bf16 V transpose: v [B,S,H,D] -> vt [B,H,D,S] ----------------
__global__ __launch_bounds__(256) void k_vtrans(const u16* __restrict__ v, u16* __restrict__ vt) {
  __shared__ u16 t[64][72];
  int bh = blockIdx.x, b = bh >> 4, h = bh & 15;
  int s0 = blockIdx.y * 64;
  int tid = threadIdx.x;
#pragma unroll
  for (int p = 0; p < 2; ++p) {
    int idx = p * 256 + tid;
    int sl = idx >> 3, c8 = (idx & 7) * 8;
    *(s8v*)(&t[sl][c8]) = *(const s8v*)(v + (((long)(b * 1024 + s0 + sl) * 16 + h) * 64) + c8);
  }
  __syncthreads();
#pragma unroll
  for (int p = 0; p < 2; ++p) {
    int idx = p * 256 + tid;
    int d = idx >> 3, c8 = (idx & 7) * 8;
    s8v o;
#pragma unroll
    for (int e = 0; e < 8; ++e) o[e] = (short)t[c8 + e][d];
    *(s8v*)(vt + ((long)bh * 64 + d) * 1024 + s0 + c8) = o;
  }
}

// ---------------- LayerNorm over E=1024, one row per block, bf16 out (LN2) ----------------
__global__ __launch_bounds__(256) void k_layernorm(const float* __restrict__ x,
                                                   const float* __restrict__ g,
                                                   const float* __restrict__ be,
                                                   u16* __restrict__ out) {
  long row = blockIdx.x;
  int tid = threadIdx.x;
  f4 v = ((const f4*)(x + row * 1024))[tid];
  float s = v[0] + v[1] + v[2] + v[3];
  float s2 = v[0] * v[0] + v[1] * v[1] + v[2] * v[2] + v[3] * v[3];
#pragma unroll
  for (int off = 32; off > 0; off >>= 1) {
    s += __shfl_down(s, off, 64);
    s2 += __shfl_down(s2, off, 64);
  }
  __shared__ float red[8];
  int wv = tid >> 6, ln = tid & 63;
  if (ln == 0) { red[wv] = s; red[4 + wv] = s2; }
  __syncthreads();
  s = red[0] + red[1] + red[2] + red[3];
  s2 = red[4] + red[5] + red[6] + red[7];
  float mean = s * (1.0f / 1024.0f);
  float var = s2 * (1.0f / 1024.0f) - mean * mean;
  float rs = rsqrtf(var + 1e-5f);
  f4 gg = ((const f4*)g)[tid];
  f4 bb = ((const f4*)be)[tid];
  u16x4 o;
#pragma unroll
  for (int i = 0; i < 4; ++i) o[i] = f2b((v[i] - mean) * rs * gg[i] + bb[i]);
  ((u16x4*)(out + row * 1024))[tid] = o;
}

// ---------------- FUSED LayerNorm1 + QKV ----------------
// One block per 64-row chunk of nx-space (= 4 (b,s) rows x 16 heads). Wave w
// layer-norms (b,s)-row blockIdx.x*4+w (full-64 shfl_xor reduce), writes
// normalized bf16 into LDS [64][72], then runs the k_qkv MFMA body (each wave
// reads only its own 16 rows). Eliminates the nx HBM round-trip (32 MB).
__global__ __launch_bounds__(256) void k_ln_qkv(
    const float* __restrict__ x, const float* __restrict__ g, const float* __restrict__ be,
    const u16* __restrict__ WqT, const u16* __restrict__ WkT, const u16* __restrict__ WvT,
    u16* __restrict__ q, u16* __restrict__ k, u16* __restrict__ v) {
  constexpr int LDP = 72;
  __shared__ u16 A[64 * LDP];
  int tid = threadIdx.x, lane = tid & 63, wave = tid >> 6;
  int quad = lane >> 4, l16 = lane & 15;
  long xrow = (long)blockIdx.x * 4 + wave;
  const f4* xp = (const f4*)(x + xrow * 1024);
  const f4* gp = (const f4*)g;
  const f4* bp = (const f4*)be;
  f4 vv[4];
  float s = 0.f, s2 = 0.f;
#pragma unroll
  for (int j = 0; j < 4; ++j) {
    vv[j] = xp[lane * 4 + j];
#pragma unroll
    for (int e = 0; e < 4; ++e) { s += vv[j][e]; s2 += vv[j][e] * vv[j][e]; }
  }
#pragma unroll
  for (int off = 1; off < 64; off <<= 1) {
    s += __shfl_xor(s, off, 64);
    s2 += __shfl_xor(s2, off, 64);
  }
  float mean = s * (1.0f / 1024.0f);
  float var = s2 * (1.0f / 1024.0f) - mean * mean;
  float rs = rsqrtf(var + 1e-5f);
  // element e_ = lane*16 + 4j + e -> LDS row wave*16 + (lane>>2), col (lane&3)*16 + 4j+e
  u16* ap = &A[(wave * 16 + (lane >> 2)) * LDP + (lane & 3) * 16];
#pragma unroll
  for (int j = 0; j < 4; ++j) {
    f4 gg = gp[lane * 4 + j], bb = bp[lane * 4 + j];
    u16x4 o;
#pragma unroll
    for (int e = 0; e < 4; ++e) o[e] = f2b((vv[j][e] - mean) * rs * gg[e] + bb[e]);
    *(u16x4*)(ap + j * 4) = o;
  }
  __syncthreads();
  s8v a0 = *(const s8v*)(&A[(wave * 16 + l16) * LDP + quad * 8]);
  s8v a1 = *(const s8v*)(&A[(wave * 16 + l16) * LDP + 32 + quad * 8]);
  long rbase = (long)blockIdx.x * 64 + wave * 16;
  const u16* Ws[3] = {WqT, WkT, WvT};
  u16* Os[3] = {q, k, v};
#pragma unroll
  for (int t = 0; t < 3; ++t) {
#pragma unroll
    for (int j = 0; j < 4; ++j) {
      s8v b0 = *(const s8v*)(Ws[t] + (j * 16 + l16) * 64 + quad * 8);
      s8v b1 = *(const s8v*)(Ws[t] + (j * 16 + l16) * 64 + 32 + quad * 8);
      f4 acc = {0.f, 0.f, 0.f, 0.f};
      acc = __builtin_amdgcn_mfma_f32_16x16x32_bf16(a0, b0, acc, 0, 0, 0);
      acc = __builtin_amdgcn_mfma_f32_16x16x32_bf16(a1, b1, acc, 0, 0, 0);
#pragma unroll
      for (int r = 0; r < 4; ++r)
        Os[t][(rbase + quad * 4 + r) * 64 + j * 16 + l16] = f2b(acc[r]);
    }
  }
}

// ---------------- MFMA flash attention (causal), T14 double-buffered K/V ----------------
// Per k-tile: issue next tile's global loads to REGISTERS before the barrier,
// compute on buf[cur], ds_write regs to buf[cur^1] after compute. Every buffer's
// last read is >=1 collective barrier before its overwrite (verified ledger).
__global__ __launch_bounds__(256) void k_attn_mfma(const u16* __restrict__ q,
                                                   const u16* __restrict__ kk,
                                                   const u16* __restrict__ vt,
                                                   u16* __restrict__ o) {
  constexpr int LDK = 72;
  __shared__ u16 Ks[2][64 * LDK];
  __shared__ u16 Vt[2][64 * LDK];
  __shared__ u16 Ps[4][16 * LDK];
  int tid = threadIdx.x, lane = tid & 63, wave = tid >> 6;
  int quad = lane >> 4, l16 = lane & 15;
  int b = blockIdx.x >> 4, h = blockIdx.x & 15;
  int qi = (int)gridDim.y - 1 - (int)blockIdx.y;
  int q0 = qi * 64 + wave * 16;

  const u16* qp = q + (((long)(b * 1024 + q0 + l16)) * 16 + h) * 64;
  s8v aq0 = *(const s8v*)(qp + quad * 8);
  s8v aq1 = *(const s8v*)(qp + 32 + quad * 8);

  // staging coords: thread covers rows srow0 and srow0+32, 16B col chunk sc8
  int srow0 = tid >> 3, sc8 = (tid & 7) * 8;
  int srow1 = srow0 + 32;
  const u16* kb_ = kk + (long)b * 1048576 + h * 64;   // + (kt*64+row)*1024 + sc8
  const u16* vb_ = vt + (long)blockIdx.x * 65536;     // + row*1024 + kt*64 + sc8

  f4 O[4];
  float m_[4], l_[4];
#pragma unroll
  for (int jd = 0; jd < 4; ++jd) O[jd] = f4{0.f, 0.f, 0.f, 0.f};
#pragma unroll
  for (int r = 0; r < 4; ++r) { m_[r] = -__builtin_inff(); l_[r] = 0.f; }

  // prologue: tile 0 -> regs -> buf0
  s8v rk0 = *(const s8v*)(kb_ + (long)srow0 * 1024 + sc8);
  s8v rk1 = *(const s8v*)(kb_ + (long)srow1 * 1024 + sc8);
  s8v rv0 = *(const s8v*)(vb_ + (long)srow0 * 1024 + sc8);
  s8v rv1 = *(const s8v*)(vb_ + (long)srow1 * 1024 + sc8);
  *(s8v*)(&Ks[0][srow0 * LDK + sc8]) = rk0;
  *(s8v*)(&Ks[0][srow1 * LDK + sc8]) = rk1;
  *(s8v*)(&Vt[0][srow0 * LDK + sc8]) = rv0;
  *(s8v*)(&Vt[0][srow1 * LDK + sc8]) = rv1;

  for (int kt = 0; kt <= qi; ++kt) {
    int cur = kt & 1;
    if (kt < qi) {  // issue next tile's loads; latency hides under compute
      long ko = (long)(kt + 1) * 64;
      rk0 = *(const s8v*)(kb_ + (ko + srow0) * 1024 + sc8);
      rk1 = *(const s8v*)(kb_ + (ko + srow1) * 1024 + sc8);
      rv0 = *(const s8v*)(vb_ + (long)srow0 * 1024 + (kt + 1) * 64 + sc8);
      rv1 = *(const s8v*)(vb_ + (long)srow1 * 1024 + (kt + 1) * 64 + sc8);
    }
    __syncthreads();  // buf[cur] writes (prev iter) complete and visible

    const u16* Kc = Ks[cur];
    const u16* Vc = Vt[cur];
    f4 sf[4];
    __builtin_amdgcn_s_setprio(1);
#pragma unroll
    for (int jn = 0; jn < 4; ++jn) {
      s8v b0 = *(const s8v*)(Kc + (jn * 16 + l16) * LDK + quad * 8);
      s8v b1 = *(const s8v*)(Kc + (jn * 16 + l16) * LDK + 32 + quad * 8);
      f4 acc = f4{0.f, 0.f, 0.f, 0.f};
      acc = __builtin_amdgcn_mfma_f32_16x16x32_bf16(aq0, b0, acc, 0, 0, 0);
      acc = __builtin_amdgcn_mfma_f32_16x16x32_bf16(aq1, b1, acc, 0, 0, 0);
      sf[jn] = acc;
    }
    __builtin_amdgcn_s_setprio(0);
    bool diag = (kt == qi);
    float rm[4];
#pragma unroll
    for (int r = 0; r < 4; ++r) rm[r] = -__builtin_inff();
#pragma unroll
    for (int jn = 0; jn < 4; ++jn)
#pragma unroll
      for (int r = 0; r < 4; ++r) {
        float v = sf[jn][r] * 0.03125f;
        if (diag && (jn * 16 + l16 > wave * 16 + quad * 4 + r)) v = -__builtin_inff();
        sf[jn][r] = v;
        rm[r] = fmaxf(rm[r], v);
      }
#pragma unroll
    for (int off = 1; off < 16; off <<= 1)
#pragma unroll
      for (int r = 0; r < 4; ++r) rm[r] = fmaxf(rm[r], __shfl_xor(rm[r], off, 64));
    float alpha[4], rs[4];
#pragma unroll
    for (int r = 0; r < 4; ++r) {
      float mn = fmaxf(m_[r], rm[r]);
      alpha[r] = __expf(m_[r] - mn);
      m_[r] = mn;
      rs[r] = 0.f;
    }
#pragma unroll
    for (int jn = 0; jn < 4; ++jn)
#pragma unroll
      for (int r = 0; r < 4; ++r) {
        float p = __expf(sf[jn][r] - m_[r]);
        rs[r] += p;
        Ps[wave][(quad * 4 + r) * LDK + jn * 16 + l16] = f2b(p);
      }
#pragma unroll
    for (int off = 1; off < 16; off <<= 1)
#pragma unroll
      for (int r = 0; r < 4; ++r) rs[r] += __shfl_xor(rs[r], off, 64);
#pragma unroll
    for (int r = 0; r < 4; ++r) l_[r] = l_[r] * alpha[r] + rs[r];
#pragma unroll
    for (int jd = 0; jd < 4; ++jd)
#pragma unroll
      for (int r = 0; r < 4; ++r) O[jd][r] *= alpha[r];
    asm volatile("s_waitcnt lgkmcnt(0)" ::: "memory");
    s8v p0 = *(const s8v*)(&Ps[wave][l16 * LDK + quad * 8]);
    s8v p1 = *(const s8v*)(&Ps[wave][l16 * LDK + 32 + quad * 8]);
    __builtin_amdgcn_s_setprio(1);
#pragma unroll
    for (int jd = 0; jd < 4; ++jd) {
      s8v b0 = *(const s8v*)(Vc + (jd * 16 + l16) * LDK + quad * 8);
      s8v b1 = *(const s8v*)(Vc + (jd * 16 + l16) * LDK + 32 + quad * 8);
      O[jd] = __builtin_amdgcn_mfma_f32_16x16x32_bf16(p0, b0, O[jd], 0, 0, 0);
      O[jd] = __builtin_amdgcn_mfma_f32_16x16x32_bf16(p1, b1, O[jd], 0, 0, 0);
    }
    __builtin_amdgcn_s_setprio(0);

    if (kt < qi) {  // write next tile into the other buffer
      int nb = cur ^ 1;
      *(s8v*)(&Ks[nb][srow0 * LDK + sc8]) = rk0;
      *(s8v*)(&Ks[nb][srow1 * LDK + sc8]) = rk1;
      *(s8v*)(&Vt[nb][srow0 * LDK + sc8]) = rv0;
      *(s8v*)(&Vt[nb][srow1 * LDK + sc8]) = rv1;
    }
  }
#pragma unroll
  for (int r = 0; r < 4; ++r) {
    float inv = 1.0f / l_[r];
    u16* op = o + (((long)(b * 1024 + q0 + quad * 4 + r)) * 16 + h) * 64;
#pragma unroll
    for (int jd = 0; jd < 4; ++jd) op[jd * 16 + l16] = f2b(O[jd][r] * inv);
  }
}

// ---------------- 256x256 8-phase GEMM, G4 swizzle (0 conflicts), default block map ----
template <int EPI>
__global__ __launch_bounds__(512) void k_gemm256(const u16* __restrict__ A,
                                                 const u16* __restrict__ BT,
                                                 const float* __restrict__ bias,
                                                 const float* __restrict__ resid,
                                                 void* __restrict__ outp, int M, int N, int K,
                                                 int lda) {
  __shared__ __align__(16) u16 S[65536];  // 128 KiB
  int tid = threadIdx.x, lane = tid & 63, wave = tid >> 6;
  int l16 = lane & 15, quad = lane >> 4;
  int wm = wave >> 2, wn = wave & 3;
  long bm = blockIdx.x, bn = blockIdx.y;
  int z = blockIdx.z;

  int rl = l16 & 7;
  int c0 = 8 * (quad ^ rl);
  int c1 = 8 * ((quad ^ 4) ^ rl);
  int rowA = (wm * 64 + l16) * 64;
  int rowB = (wn * 32 + l16) * 64;

  int Lb = tid * 16;
  int Ls = Lb ^ (((Lb >> 7) & 7) << 4);
  int r_ = Ls >> 7, kin = (Ls & 127) >> 1;
  const u16* pA = A + (bm * 256 + r_) * (long)lda + kin + (long)z * K;
  const u16* pB = BT + (bn * 256 + r_) * (long)lda + kin + (long)z * K;

  f4 acc[4][4][2];
#pragma unroll
  for (int q = 0; q < 4; ++q)
#pragma unroll
    for (int mi = 0; mi < 4; ++mi)
#pragma unroll
      for (int nj = 0; nj < 2; ++nj) acc[q][mi][nj] = f4{0.f, 0.f, 0.f, 0.f};
  s8v aF[4][2], bF[2][2][2];

#define BAR asm volatile("s_barrier" ::: "memory")
#define LGK0 asm volatile("s_waitcnt lgkmcnt(0)" ::: "memory")
#define WVM4 asm volatile("s_waitcnt vmcnt(4)" ::: "memory")
#define WVM0 asm volatile("s_waitcnt vmcnt(0)" ::: "memory")

#define STAGE(mat, half, t, buf)                                               \
  do {                                                                         \
    const u16* g_ = ((mat) ? pB : pA) + (long)(half) * 128 * lda + (t) * 64;   \
    char* l_ = ((char*)S) + ((buf) * 32768 + (mat) * 16384 + (half) * 8192) * 2 + wave * 1024; \
    GLD_LDS16(g_, l_);                                                         \
    GLD_LDS16(g_ + 64 * (long)lda, l_ + 8192);                                 \
  } while (0)

#define LDA(buf, mh)                                                           \
  do {                                                                         \
    const u16* p_ = S + (buf) * 32768 + (mh) * 8192 + rowA;                    \
    _Pragma("unroll") for (int mi = 0; mi < 4; ++mi) {                         \
      aF[mi][0] = *(const s8v*)(p_ + mi * 1024 + c0);                          \
      aF[mi][1] = *(const s8v*)(p_ + mi * 1024 + c1);                          \
    }                                                                          \
  } while (0)

#define LDB(buf, nh, set)                                                      \
  do {                                                                         \
    const u16* p_ = S + (buf) * 32768 + 16384 + (nh) * 8192 + rowB;            \
    _Pragma("unroll") for (int nj = 0; nj < 2; ++nj) {                         \
      bF[set][nj][0] = *(const s8v*)(p_ + nj * 1024 + c0);                     \
      bF[set][nj][1] = *(const s8v*)(p_ + nj * 1024 + c1);                     \
    }                                                                          \
  } while (0)

#define MM(q)                                                                  \
  do {                                                                         \
    _Pragma("unroll") for (int mi = 0; mi < 4; ++mi)                           \
        _Pragma("unroll") for (int nj = 0; nj < 2; ++nj) {                     \
      acc[q][mi][nj] = __builtin_amdgcn_mfma_f32_16x16x32_bf16(                \
          aF[mi][0], bF[(q) & 1][nj][0], acc[q][mi][nj], 0, 0, 0);             \
      acc[q][mi][nj] = __builtin_amdgcn_mfma_f32_16x16x32_bf16(                \
          aF[mi][1], bF[(q) & 1][nj][1], acc[q][mi][nj], 0, 0, 0);             \
    }                                                                          \
  } while (0)

#define PHASES(t, LAST)                                                        \
  LDA(0, 0); LDB(0, 0, 0); STAGE(0, 1, (t) + 1, 1);                            \
  BAR; LGK0; __builtin_amdgcn_s_setprio(1); MM(0); __builtin_amdgcn_s_setprio(0); BAR; \
  LDB(0, 1, 1); STAGE(1, 1, (t) + 1, 1);                                       \
  BAR; LGK0; __builtin_amdgcn_s_setprio(1); MM(1); __builtin_amdgcn_s_setprio(0); BAR; \
  LDA(0, 1); if (!(LAST)) STAGE(0, 0, (t) + 2, 0);                             \
  BAR; LGK0; __builtin_amdgcn_s_setprio(1); MM(2); __builtin_amdgcn_s_setprio(0); BAR; \
  if (!(LAST)) STAGE(1, 0, (t) + 2, 0);                                        \
  __builtin_amdgcn_s_setprio(1); MM(3); __builtin_amdgcn_s_setprio(0);         \
  if (LAST) { WVM0; } else { WVM4; }                                           \
  BAR;                                                                         \
  LDA(1, 0); LDB(1, 0, 0); if (!(LAST)) STAGE(0, 1, (t) + 2, 0);               \
  BAR; LGK0; __builtin_amdgcn_s_setprio(1); MM(0); __builtin_amdgcn_s_setprio(0); BAR; \
  LDB(1, 1, 1); if (!(LAST)) STAGE(1, 1, (t) + 2, 0);                          \
  BAR; LGK0; __builtin_amdgcn_s_setprio(1); MM(1); __builtin_amdgcn_s_setprio(0); BAR; \
  LDA(1, 1); if (!(LAST)) STAGE(0, 0, (t) + 3, 1);                             \
  BAR; LGK0; __builtin_amdgcn_s_setprio(1); MM(2); __builtin_amdgcn_s_setprio(0); BAR; \
  if (!(LAST)) STAGE(1, 0, (t) + 3, 1);                                        \
  __builtin_amdgcn_s_setprio(1); MM(3); __builtin_amdgcn_s_setprio(0);         \
  if (!(LAST)) { WVM4; BAR; }

  STAGE(0, 0, 0, 0);
  STAGE(1, 0, 0, 0);
  STAGE(0, 1, 0, 0);
  STAGE(1, 1, 0, 0);
  STAGE(0, 0, 1, 1);
  STAGE(1, 0, 1, 1);
  WVM4; BAR;

  int NI = K >> 7;
  for (int i = 0; i < NI - 1; ++i) {
    int t = 2 * i;
    PHASES(t, 0);
  }
  {
    int t = 2 * (NI - 1);
    PHASES(t, 1);
  }

#undef PHASES
#undef MM
#undef LDB
#undef LDA
#undef STAGE
#undef WVM0
#undef WVM4
#undef LGK0
#undef BAR

  float* P0 = (EPI == 0) ? ((float*)outp + (long)z * M * N) : nullptr;
#pragma unroll
  for (int q = 0; q < 4; ++q) {
    int mh = q >> 1, nh = q & 1;
#pragma unroll
    for (int mi = 0; mi < 4; ++mi) {
#pragma unroll
      for (int nj = 0; nj < 2; ++nj) {
        long row = bm * 256 + mh * 128 + wm * 64 + mi * 16 + quad * 4;
        int col = (int)bn * 256 + nh * 128 + wn * 32 + nj * 16 + l16;
        float bcol = 0.f;
        if (EPI != 0) bcol = bias[col];
#pragma unroll
        for (int rr = 0; rr < 4; ++rr) {
          float val = acc[q][mi][nj][rr] + bcol;
          if (EPI == 0) {
            P0[(row + rr) * (long)N + col] = val;
          } else if (EPI == 1) {
            ((u16*)outp)[(row + rr) * (long)N + col] = f2b(val > 0.f ? val : 0.f);
          } else {
            ((float*)outp)[(row + rr) * (long)N + col] =
                resid[(row + rr) * (long)N + col] + val;
          }
        }
      }
    }
  }
}

// ---------------- 256x128 4-phase GEMM, default block map ----------------
__global__ __launch_bounds__(512) void k_gemm256n128(const u16* __restrict__ A,
                                                     const u16* __restrict__ BT,
                                                     const float* __restrict__ bias,
                                                     const float* __restrict__ resid,
                                                     float* __restrict__ outp,
                                                     int M, int N, int K, int lda) {
  __shared__ __align__(16) u16 S[49152];  // 96 KiB: [buf][A0|A1|B][128][64]
  int tid = threadIdx.x, lane = tid & 63, wave = tid >> 6;
  int l16 = lane & 15, quad = lane >> 4;
  int wm = wave >> 1, wn = wave & 1;
  long bm = blockIdx.x, bn = blockIdx.y;

  int rl = l16 & 7;
  int c0 = 8 * (quad ^ rl);
  int c1 = 8 * ((quad ^ 4) ^ rl);
  int rowA = (wm >> 1) * 8192 + ((wm & 1) * 64 + l16) * 64;
  int rowB = 16384 + (wn * 64 + l16) * 64;

  int Lb = tid * 16;
  int Ls = Lb ^ (((Lb >> 7) & 7) << 4);
  int r_ = Ls >> 7, kin = (Ls & 127) >> 1;
  const u16* pA = A + (bm * 256 + r_) * (long)lda + kin;
  const u16* pB = BT + (bn * 128 + r_) * (long)lda + kin;

  f4 acc[4][4];
#pragma unroll
  for (int mi = 0; mi < 4; ++mi)
#pragma unroll
    for (int nj = 0; nj < 4; ++nj) acc[mi][nj] = f4{0.f, 0.f, 0.f, 0.f};
  s8v aF[4][2], bF[2][2];

#define BAR asm volatile("s_barrier" ::: "memory")
#define LGK0 asm volatile("s_waitcnt lgkmcnt(0)" ::: "memory")
#define WVM4 asm volatile("s_waitcnt vmcnt(4)" ::: "memory")
#define WVM0 asm volatile("s_waitcnt vmcnt(0)" ::: "memory")

#define STAGEA(t, buf)                                                         \
  do {                                                                         \
    const u16* g_ = pA + (t) * 64;                                             \
    char* l_ = ((char*)S) + (buf) * 49152 + wave * 1024;                       \
    GLD_LDS16(g_, l_);                                                         \
    GLD_LDS16(g_ + 64 * (long)lda, l_ + 8192);                                 \
    GLD_LDS16(g_ + 128 * (long)lda, l_ + 16384);                               \
    GLD_LDS16(g_ + 192 * (long)lda, l_ + 24576);                               \
  } while (0)

#define STAGEB(t, buf)                                                         \
  do {                                                                         \
    const u16* g_ = pB + (t) * 64;                                             \
    char* l_ = ((char*)S) + (buf) * 49152 + 32768 + wave * 1024;               \
    GLD_LDS16(g_, l_);                                                         \
    GLD_LDS16(g_ + 64 * (long)lda, l_ + 8192);                                 \
  } while (0)

#define LDAn(buf)                                                              \
  do {                                                                         \
    const u16* p_ = S + (buf) * 24576 + rowA;                                  \
    _Pragma("unroll") for (int mi = 0; mi < 4; ++mi) {                         \
      aF[mi][0] = *(const s8v*)(p_ + mi * 1024 + c0);                          \
      aF[mi][1] = *(const s8v*)(p_ + mi * 1024 + c1);                          \
    }                                                                          \
  } while (0)

#define LDBn(buf, nh)                                                          \
  do {                                                                         \
    const u16* p_ = S + (buf) * 24576 + rowB + (nh) * 2048;                    \
    _Pragma("unroll") for (int nj2 = 0; nj2 < 2; ++nj2) {                      \
      bF[nj2][0] = *(const s8v*)(p_ + nj2 * 1024 + c0);                        \
      bF[nj2][1] = *(const s8v*)(p_ + nj2 * 1024 + c1);                        \
    }                                                                          \
  } while (0)

#define MMn(nh)                                                                \
  do {                                                                         \
    _Pragma("unroll") for (int mi = 0; mi < 4; ++mi)                           \
        _Pragma("unroll") for (int nj2 = 0; nj2 < 2; ++nj2) {                  \
      acc[mi][(nh) * 2 + nj2] = __builtin_amdgcn_mfma_f32_16x16x32_bf16(       \
          aF[mi][0], bF[nj2][0], acc[mi][(nh) * 2 + nj2], 0, 0, 0);            \
      acc[mi][(nh) * 2 + nj2] = __builtin_amdgcn_mfma_f32_16x16x32_bf16(       \
          aF[mi][1], bF[nj2][1], acc[mi][(nh) * 2 + nj2], 0, 0, 0);            \
    }                                                                          \
  } while (0)

#define PHASES(t, LAST)                                                        \
  LDAn(0); LDBn(0, 0); STAGEB((t) + 1, 1);                                     \
  BAR; LGK0; __builtin_amdgcn_s_setprio(1); MMn(0); __builtin_amdgcn_s_setprio(0); BAR; \
  LDBn(0, 1); if (!(LAST)) STAGEA((t) + 2, 0);                                 \
  BAR; LGK0; __builtin_amdgcn_s_setprio(1); MMn(1); __builtin_amdgcn_s_setprio(0); \
  if (LAST) { WVM0; } else { WVM4; }                                           \
  BAR;                                                                         \
  LDAn(1); LDBn(1, 0); if (!(LAST)) STAGEB((t) + 2, 0);                        \
  BAR; LGK0; __builtin_amdgcn_s_setprio(1); MMn(0); __builtin_amdgcn_s_setprio(0); BAR; \
  LDBn(1, 1); if (!(LAST)) STAGEA((t) + 3, 1);                                 \
  BAR; LGK0; __builtin_amdgcn_s_setprio(1); MMn(1); __builtin_amdgcn_s_setprio(0); \
  if (!(LAST)) { WVM4; }                                                       \
  BAR;

  STAGEA(0, 0);
  STAGEB(0, 0);
  STAGEA(1, 1);
  WVM4; BAR;

  int NI = K >> 7;
  for (int i = 0; i < NI - 1; ++i) {
    int t = 2 * i;
    PHASES(t, 0);
  }
  {
    int t = 2 * (NI - 1);
    PHASES(t, 1);
  }

#undef PHASES
#undef MMn
#undef LDBn
#undef LDAn
#undef STAGEB
#undef STAGEA
#undef WVM0
#undef WVM4
#undef LGK0
#undef BAR

#pragma unroll
  for (int mi = 0; mi < 4; ++mi) {
#pragma unroll
    for (int nj = 0; nj < 4; ++nj) {
      long row = bm * 256 + wm * 64 + mi * 16 + quad * 4;
      int col = (int)bn * 128 + wn * 64 + nj * 16 + l16;
      float bcol = bias[col];
#pragma unroll
      for (int rr = 0; rr < 4; ++rr) {
        outp[(row + rr) * (long)N + col] =
            resid[(row + rr) * (long)N + col] + acc[mi][nj][rr] + bcol;
      }
    }
  }
}

extern "C" void kernel_launch(void* const* d_in, const int* in_sizes, int n_in, void* d_out,
                              int out_size, void* d_ws, size_t ws_size, hipStream_t stream) {
  const float* x = (const float*)d_in[0];
  const float* Wq = (const float*)d_in[1];
  const float* Wk = (const float*)d_in[2];
  const float* Wv = (const float*)d_in[3];
  const float* Wo = (const float*)d_in[4];
  const float* bo = (const float*)d_in[5];
  const float* W1 = (const float*)d_in[6];
  const float* b1 = (const float*)d_in[7];
  const float* W2 = (const float*)d_in[8];
  const float* b2 = (const float*)d_in[9];
  const float* g1 = (const float*)d_in[10];
  const float* be1 = (const float*)d_in[11];
  const float* g2 = (const float*)d_in[12];
  const float* be2 = (const float*)d_in[13];

  char* ws = (char*)d_ws;
  const size_t MB = 1ull << 20;
  u16* nx = (u16*)(ws + 0);            // 16 MB  attn out (LN1 buffer no longer written)
  u16* qb = (u16*)(ws + 16 * MB);      // 16 MB  q; reused as nx2
  u16* kb = (u16*)(ws + 32 * MB);      // 16 MB
  u16* vb = (u16*)(ws + 48 * MB);      // 16 MB
  float* x1 = (float*)(ws + 64 * MB);  // 32 MB  attn-sublayer output (fp32 residual)
  u16* h1 = (u16*)(ws + 96 * MB);      // 64 MB  MLP hidden (after attn)
  u16* vtr = (u16*)(ws + 96 * MB);     // 16 MB  V^T [B,H,D,S]; dead before h1 is written
  u16* WoT = (u16*)(ws + 160 * MB);    // 2 MB
  u16* W1T = (u16*)(ws + 162 * MB);    // 8 MB
  u16* W2T = (u16*)(ws + 170 * MB);    // 8 MB
  u16* WqT = (u16*)(ws + 178 * MB);
  u16* WkT = WqT + 64 * 64;
  u16* WvT = WkT + 64 * 64;
  u16* ob = nx;
  u16* nx2 = qb;

  k_transpose_all<<<9228, 256, 0, stream>>>(Wo, W1, W2, Wq, Wk, Wv, WoT, W1T, W2T, WqT, WkT, WvT);

  k_ln_qkv<<<2048, 256, 0, stream>>>(x, g1, be1, WqT, WkT, WvT, qb, kb, vb);
  k_vtrans<<<dim3(128, 16), 256, 0, stream>>>(vb, vtr);
  k_attn_mfma<<<dim3(128, 16), 256, 0, stream>>>(qb, kb, vtr, ob);
  k_gemm256n128<<<dim3(32, 8), 512, 0, stream>>>(ob, WoT, bo, x, x1, 8192, 1024, 1024, 1024);

  k_layernorm<<<8192, 256, 0, stream>>>(x1, g2, be2, nx2);
  k_gemm256<1><<<dim3(32, 16, 1), 512, 0, stream>>>(nx2, W1T, b1, nullptr, h1, 8192, 4096, 1024, 1024);
  k_gemm256n128<<<dim3(32, 8), 512, 0, stream>>>(h1, W2T, b2, x1, (float*)d_out, 8192, 1024, 4096, 4096);
}